// Round 1
// baseline (457.878 us; speedup 1.0000x reference)
//
#include <hip/hip_runtime.h>

typedef __attribute__((ext_vector_type(8))) short  shortx8;  // 8 x bf16 (4 VGPR)
typedef __attribute__((ext_vector_type(4))) float  floatx4;  // MFMA C/D

#define B_SZ 128
#define I_SZ 64
#define K_SZ 1024
#define O_SZ 1024
#define IK   (I_SZ * K_SZ)   // 65536: stride of b in x, of o in weight
#define OI   (O_SZ * I_SZ)   // 65536: stride of b in out
#define BK   32
#define NKT  (K_SZ / BK)     // 32

// fp32 -> bf16 round-to-nearest-even (inputs are finite; no NaN handling needed)
__device__ __forceinline__ unsigned short f2bf(float f) {
    unsigned int u = __builtin_bit_cast(unsigned int, f);
    u += 0x7fffu + ((u >> 16) & 1u);
    return (unsigned short)(u >> 16);
}

__device__ __forceinline__ shortx8 cvt8(float4 a, float4 b) {
    shortx8 r;
    r[0] = (short)f2bf(a.x); r[1] = (short)f2bf(a.y);
    r[2] = (short)f2bf(a.z); r[3] = (short)f2bf(a.w);
    r[4] = (short)f2bf(b.x); r[5] = (short)f2bf(b.y);
    r[6] = (short)f2bf(b.z); r[7] = (short)f2bf(b.w);
    return r;
}

// grid = 512 (64 i-slices x 8 o-tiles of 128), block = 256 (4 waves, 2x2)
// wave tile 64x64, fragments 16x16x32 bf16, K-loop depth-1 register prefetch.
__global__ __launch_bounds__(256, 2) void factlin_mfma(
    const float* __restrict__ x, const float* __restrict__ w,
    const float* __restrict__ bias, float* __restrict__ out)
{
    const int wg   = blockIdx.x;
    const int nt   = wg & 7;   // o-tile; same nt -> same XCD (write-line merging in L2)
    const int i    = wg >> 3;  // factor index
    const int lane = threadIdx.x & 63;
    const int wid  = threadIdx.x >> 6;
    const int wm   = wid >> 1;            // wave row  (b direction)
    const int wn   = wid & 1;             // wave col  (o direction)
    const int lrow  = lane & 15;          // A row / B col within 16x16 frag
    const int khalf = (lane >> 4) * 8;    // k sub-slice owned by this lane group

    // per-lane base pointers; A/B fragments are 8 contiguous fp32 per lane
    const float* ap = x + (wm * 64 + lrow) * IK + i * K_SZ + khalf;
    const float* bp = w + (nt * 128 + wn * 64 + lrow) * IK + i * K_SZ + khalf;

    float4 abuf[4][2];
    float4 bbuf[4][2];

    #pragma unroll
    for (int mi = 0; mi < 4; ++mi) {
        abuf[mi][0] = *(const float4*)(ap + mi * (16 * IK));
        abuf[mi][1] = *(const float4*)(ap + mi * (16 * IK) + 4);
        bbuf[mi][0] = *(const float4*)(bp + mi * (16 * IK));
        bbuf[mi][1] = *(const float4*)(bp + mi * (16 * IK) + 4);
    }

    floatx4 acc[4][4] = {};

    #pragma unroll 1
    for (int kt = 0; kt < NKT; ++kt) {
        // convert current K-slice to bf16 fragments (this is where vmcnt waits land)
        shortx8 af[4], bf[4];
        #pragma unroll
        for (int mi = 0; mi < 4; ++mi) af[mi] = cvt8(abuf[mi][0], abuf[mi][1]);
        #pragma unroll
        for (int ni = 0; ni < 4; ++ni) bf[ni] = cvt8(bbuf[ni][0], bbuf[ni][1]);

        // issue next K-slice loads BEFORE the MFMA block: latency hides under MFMAs
        if (kt + 1 < NKT) {
            const float* ap2 = ap + (kt + 1) * BK;
            const float* bp2 = bp + (kt + 1) * BK;
            #pragma unroll
            for (int mi = 0; mi < 4; ++mi) {
                abuf[mi][0] = *(const float4*)(ap2 + mi * (16 * IK));
                abuf[mi][1] = *(const float4*)(ap2 + mi * (16 * IK) + 4);
                bbuf[mi][0] = *(const float4*)(bp2 + mi * (16 * IK));
                bbuf[mi][1] = *(const float4*)(bp2 + mi * (16 * IK) + 4);
            }
        }

        #pragma unroll
        for (int mi = 0; mi < 4; ++mi)
            #pragma unroll
            for (int ni = 0; ni < 4; ++ni)
                acc[mi][ni] = __builtin_amdgcn_mfma_f32_16x16x32_bf16(
                    af[mi], bf[ni], acc[mi][ni], 0, 0, 0);
    }

    // epilogue: D layout (m89-verified): col = lane&15, row = (lane>>4)*4 + reg
    const int obase = nt * 128 + wn * 64;
    float bv[4];
    #pragma unroll
    for (int ni = 0; ni < 4; ++ni)
        bv[ni] = bias[(obase + ni * 16 + lrow) * I_SZ + i];

    const int rb = wm * 64 + (lane >> 4) * 4;
    #pragma unroll
    for (int mi = 0; mi < 4; ++mi) {
        #pragma unroll
        for (int ni = 0; ni < 4; ++ni) {
            const int ocol = obase + ni * 16 + lrow;
            float* op = out + (rb + mi * 16) * OI + ocol * I_SZ + i;
            #pragma unroll
            for (int r = 0; r < 4; ++r)
                op[r * OI] = acc[mi][ni][r] + bv[ni];
        }
    }
}

extern "C" void kernel_launch(void* const* d_in, const int* in_sizes, int n_in,
                              void* d_out, int out_size, void* d_ws, size_t ws_size,
                              hipStream_t stream) {
    const float* x  = (const float*)d_in[0];   // [128][64][1024] fp32
    const float* w  = (const float*)d_in[1];   // [1024][64][1024] fp32
    const float* b  = (const float*)d_in[2];   // [1024][64] fp32
    float* out      = (float*)d_out;           // [128][1024][64] fp32

    factlin_mfma<<<dim3(512), dim3(256), 0, stream>>>(x, w, b, out);
}